// Round 1
// baseline (695.452 us; speedup 1.0000x reference)
//
#include <hip/hip_runtime.h>

// out[16384,16] = x[16384,8192] @ W[8192,16], all fp32. Memory-bound (x = 512 MiB).
// Design: W staged through LDS in 16KB K-tiles (double-buffered, XOR-swizzled to
// be bank-conflict-free for both the cooperative write and the per-lane row read).
// Each wave owns 8 rows; lane t owns k in {4t..4t+3} within each 256-k tile;
// acc[8][16] fp32 in registers; log2 bisection cross-lane reduce; coalesced stores.

#define BATCH      16384
#define K_DIM      8192
#define OUT_DIM    16
#define KT         256                  // k's per LDS tile
#define NT         (K_DIM / KT)         // 32 tiles
#define RPW        8                    // rows per wave
#define RPB        32                   // rows per block (4 waves * 8)

__global__ __launch_bounds__(256, 2)
void NN_48696339202344_kernel(const float* __restrict__ x,
                              const float* __restrict__ W,
                              float* __restrict__ out) {
    // 2 buffers * 1024 chunks * 16B = 32 KB
    __shared__ float4 lds[2 * 1024];

    const int u    = threadIdx.x;   // 0..255
    const int wave = u >> 6;        // 0..3
    const int lane = u & 63;        // 0..63
    const int rb   = blockIdx.x * RPB + wave * RPW;  // this wave's first row

    const float4* __restrict__ Wv = (const float4*)W;   // 32768 16B chunks

    float acc[RPW][OUT_DIM];
    #pragma unroll
    for (int r = 0; r < RPW; ++r)
        #pragma unroll
        for (int o = 0; o < OUT_DIM; ++o) acc[r][o] = 0.f;

    // Per-row x base pointers (lane offset folded in).
    const float* xrow[RPW];
    #pragma unroll
    for (int r = 0; r < RPW; ++r)
        xrow[r] = x + (size_t)(rb + r) * K_DIM + 4 * lane;

    // ---- prologue: stage tile 0 into buffer 0 ----
    {
        float4 st[4];
        #pragma unroll
        for (int q = 0; q < 4; ++q) st[q] = Wv[q * 256 + u];
        #pragma unroll
        for (int q = 0; q < 4; ++q) {
            const int m   = q * 256 + u;            // 16B-chunk id within tile
            const int pos = m ^ ((m >> 4) & 7);     // bank swizzle
            lds[pos] = st[q];
        }
    }
    __syncthreads();

    for (int i = 0; i < NT; ++i) {
        const int cur = i & 1;
        const int k0  = i * KT;

        // stage next W tile into regs (overlaps compute)
        float4 st[4];
        if (i + 1 < NT) {
            #pragma unroll
            for (int q = 0; q < 4; ++q)
                st[q] = Wv[(i + 1) * 1024 + q * 256 + u];
        }

        // x: one float4 per row (fully coalesced: 64 lanes * 16B contiguous)
        float4 xv[RPW];
        #pragma unroll
        for (int r = 0; r < RPW; ++r)
            xv[r] = *(const float4*)(xrow[r] + k0);

        // compute: lane's k = k0 + 4*lane + j
        #pragma unroll
        for (int j = 0; j < 4; ++j) {
            const int kl = 4 * lane + j;            // row within tile
            float4 w4[4];
            #pragma unroll
            for (int c = 0; c < 4; ++c) {
                const int m   = kl * 4 + c;
                const int pos = m ^ ((m >> 4) & 7);
                w4[c] = lds[cur * 1024 + pos];
            }
            const float* wf = (const float*)w4;     // W[k][0..15]
            #pragma unroll
            for (int r = 0; r < RPW; ++r) {
                const float xs = ((const float*)&xv[r])[j];
                #pragma unroll
                for (int o = 0; o < OUT_DIM; ++o)
                    acc[r][o] = fmaf(xs, wf[o], acc[r][o]);
            }
        }

        // write staged tile into the other buffer
        if (i + 1 < NT) {
            const int nxt = cur ^ 1;
            #pragma unroll
            for (int q = 0; q < 4; ++q) {
                const int m   = q * 256 + u;
                const int pos = m ^ ((m >> 4) & 7);
                lds[nxt * 1024 + pos] = st[q];
            }
        }
        __syncthreads();
    }

    // ---- epilogue: reduce 2 sets of 64 values across 64 lanes ----
    // Set A: rows rb..rb+3 (value v = r*16+o); set B: rows rb+4..rb+7.
    #pragma unroll
    for (int s = 0; s < 2; ++s) {
        float vals[64];
        #pragma unroll
        for (int r = 0; r < 4; ++r)
            #pragma unroll
            for (int o = 0; o < OUT_DIM; ++o)
                vals[r * 16 + o] = acc[s * 4 + r][o];

        // bisection reduce: after all steps, lane l holds total of value l
        #pragma unroll
        for (int d = 32; d >= 1; d >>= 1) {
            const bool hi = (lane & d) != 0;
            #pragma unroll
            for (int idx = 0; idx < d; ++idx) {
                const float keep = hi ? vals[idx + d] : vals[idx];
                const float send = hi ? vals[idx]     : vals[idx + d];
                const float recv = __shfl_xor(send, d, 64);
                vals[idx] = keep + recv;
            }
        }
        // rows rb+s*4 .. rb+s*4+3: out index = (rb+s*4)*16 + lane (coalesced 256B)
        out[(size_t)(rb + s * 4) * OUT_DIM + lane] = vals[0];
    }
}

extern "C" void kernel_launch(void* const* d_in, const int* in_sizes, int n_in,
                              void* d_out, int out_size, void* d_ws, size_t ws_size,
                              hipStream_t stream) {
    const float* x = (const float*)d_in[0];
    const float* W = (const float*)d_in[1];
    float* out     = (float*)d_out;
    dim3 grid(BATCH / RPB);   // 512 blocks
    dim3 block(256);
    NN_48696339202344_kernel<<<grid, block, 0, stream>>>(x, W, out);
}